// Round 10
// baseline (685.107 us; speedup 1.0000x reference)
//
#include <hip/hip_runtime.h>
#include <hip/hip_bf16.h>

#define N_NODES 30000
#define N_EDGES 480000
#define DIM 512
#define NREL 4
#define NSEG (NREL * N_NODES)   // 120000
#define KTOT ((NREL + 1) * DIM) // 2560
#define NT (KTOT / 64)          // 40 K-tiles of 64
#define NBM ((N_NODES + 127) / 128)  // 235
#define NWG_GEMM (NBM * 4)           // 940

typedef __attribute__((ext_vector_type(8))) short short8;
typedef __attribute__((ext_vector_type(4))) float f32x4;

__device__ __forceinline__ float bf2f(unsigned int hi) {
    union { unsigned int u; float f; } v; v.u = hi << 16; return v.f;
}
__device__ __forceinline__ unsigned short f2bf(float f) {
    union { float f; unsigned int u; } v; v.f = f;
    unsigned int u = v.u;
    unsigned int r = (u + 0x7fffu + ((u >> 16) & 1u)) >> 16;
    return (unsigned short)r;
}

// ---------------- prep: WcatT build (B^T layout: [e][k], k<512 -> root, else W[r]) -----
__global__ void k_wcat(const float* __restrict__ W, const float* __restrict__ root,
                       unsigned short* __restrict__ wt) {
    int i = blockIdx.x * 256 + threadIdx.x;       // over 512*2560, k fastest
    if (i >= DIM * KTOT) return;
    int k = i % KTOT, e = i / KTOT;
    float v;
    if (k < DIM) {
        v = root[k * DIM + e];
    } else {
        int kk = k - DIM;
        int r = kk >> 9; kk &= 511;
        v = W[(size_t)r * DIM * DIM + (size_t)kk * DIM + e];
    }
    wt[(size_t)e * KTOT + k] = f2bf(v);
}

// ---------------- prep: x0 = emb[x_idx] (bf16 only); 4 nodes per 256-thread block ----
__global__ void k_embed(const int* __restrict__ xidx, const float* __restrict__ emb,
                        unsigned short* __restrict__ xb) {
    int n = blockIdx.x * 4 + (threadIdx.x >> 6);   // 7500 blocks
    int l = threadIdx.x & 63;
    if (n >= N_NODES) return;
    int id = xidx[n];
    const float4* er = (const float4*)(emb + (size_t)id * DIM + l * 8);
    float4 a = er[0], b = er[1];
    ushort4 pa, pb;
    pa.x = f2bf(a.x); pa.y = f2bf(a.y); pa.z = f2bf(a.z); pa.w = f2bf(a.w);
    pb.x = f2bf(b.x); pb.y = f2bf(b.y); pb.z = f2bf(b.z); pb.w = f2bf(b.w);
    ushort4* xbo = (ushort4*)(xb + (size_t)n * DIM + l * 8);
    xbo[0] = pa; xbo[1] = pb;
}

// ---------------- counting sort of edges by seg = etype*N + dst ----------------
__global__ void k_hist(const int* __restrict__ etype, const int* __restrict__ dst,
                       int* __restrict__ hist) {
    int e = blockIdx.x * 256 + threadIdx.x;
    if (e < N_EDGES) atomicAdd(&hist[etype[e] * N_NODES + dst[e]], 1);
}

__global__ void k_scan1(const int* __restrict__ hist, int* __restrict__ offsets,
                        int* __restrict__ bsums) {
    __shared__ int sdata[256];
    int t = threadIdx.x, b = blockIdx.x;
    int base = b * 2048 + t * 8;
    int v[8]; int s = 0;
    #pragma unroll
    for (int i = 0; i < 8; i++) {
        int idx = base + i;
        v[i] = (idx < NSEG) ? hist[idx] : 0;
        s += v[i];
    }
    sdata[t] = s; __syncthreads();
    for (int off = 1; off < 256; off <<= 1) {
        int x = (t >= off) ? sdata[t - off] : 0;
        __syncthreads();
        sdata[t] += x;
        __syncthreads();
    }
    int run = (t == 0) ? 0 : sdata[t - 1];
    #pragma unroll
    for (int i = 0; i < 8; i++) {
        run += v[i];
        int idx = base + i;
        if (idx < NSEG) offsets[idx + 1] = run;
    }
    if (t == 255) bsums[b] = sdata[255];
}

__global__ void k_scan2(int* __restrict__ bsums, int nb) {
    if (threadIdx.x == 0 && blockIdx.x == 0) {
        int run = 0;
        for (int i = 0; i < nb; i++) { int v = bsums[i]; bsums[i] = run; run += v; }
    }
}

__global__ void k_scan3(const int* __restrict__ bsums, int* __restrict__ offsets) {
    int t = threadIdx.x, b = blockIdx.x;
    int base = b * 2048 + t * 8;
    int add = bsums[b];
    #pragma unroll
    for (int i = 0; i < 8; i++) {
        int idx = base + i;
        if (idx < NSEG) offsets[idx + 1] += add;
    }
    if (b == 0 && t == 0) offsets[0] = 0;
}

__global__ void k_scatter(const int* __restrict__ etype, const int* __restrict__ src,
                          const int* __restrict__ dst, const int* __restrict__ offsets,
                          int* __restrict__ cursor, int* __restrict__ ssrc) {
    int e = blockIdx.x * 256 + threadIdx.x;
    if (e < N_EDGES) {
        int seg = etype[e] * N_NODES + dst[e];
        int p = atomicAdd(&cursor[seg], 1);
        ssrc[offsets[seg] + p] = src[e];
    }
}

// ---------------- per-layer segment-mean (reads bf16 x, writes bf16 mean) ----------------
__global__ __launch_bounds__(256) void k_agg(const unsigned short* __restrict__ xb,
                                             const int* __restrict__ ssrc,
                                             const int* __restrict__ offsets,
                                             unsigned short* __restrict__ meanb) {
    int wid = threadIdx.x >> 6, lane = threadIdx.x & 63;
    int seg = blockIdx.x * 4 + wid;
    int st = offsets[seg], en = offsets[seg + 1];
    float acc[8] = {0, 0, 0, 0, 0, 0, 0, 0};
    int i = st;
    for (; i + 1 < en; i += 2) {
        int s0 = ssrc[i], s1 = ssrc[i + 1];
        uint4 v0 = *(const uint4*)(xb + (size_t)s0 * DIM + lane * 8);
        uint4 v1 = *(const uint4*)(xb + (size_t)s1 * DIM + lane * 8);
        acc[0] += bf2f(v0.x & 0xffffu) + bf2f(v1.x & 0xffffu);
        acc[1] += bf2f(v0.x >> 16)     + bf2f(v1.x >> 16);
        acc[2] += bf2f(v0.y & 0xffffu) + bf2f(v1.y & 0xffffu);
        acc[3] += bf2f(v0.y >> 16)     + bf2f(v1.y >> 16);
        acc[4] += bf2f(v0.z & 0xffffu) + bf2f(v1.z & 0xffffu);
        acc[5] += bf2f(v0.z >> 16)     + bf2f(v1.z >> 16);
        acc[6] += bf2f(v0.w & 0xffffu) + bf2f(v1.w & 0xffffu);
        acc[7] += bf2f(v0.w >> 16)     + bf2f(v1.w >> 16);
    }
    if (i < en) {
        int s = ssrc[i];
        uint4 v = *(const uint4*)(xb + (size_t)s * DIM + lane * 8);
        acc[0] += bf2f(v.x & 0xffffu); acc[1] += bf2f(v.x >> 16);
        acc[2] += bf2f(v.y & 0xffffu); acc[3] += bf2f(v.y >> 16);
        acc[4] += bf2f(v.z & 0xffffu); acc[5] += bf2f(v.z >> 16);
        acc[6] += bf2f(v.w & 0xffffu); acc[7] += bf2f(v.w >> 16);
    }
    float inv = (en > st) ? 1.0f / (float)(en - st) : 0.0f;
    uint4 o;
    o.x = (unsigned int)f2bf(acc[0] * inv) | ((unsigned int)f2bf(acc[1] * inv) << 16);
    o.y = (unsigned int)f2bf(acc[2] * inv) | ((unsigned int)f2bf(acc[3] * inv) << 16);
    o.z = (unsigned int)f2bf(acc[4] * inv) | ((unsigned int)f2bf(acc[5] * inv) << 16);
    o.w = (unsigned int)f2bf(acc[6] * inv) | ((unsigned int)f2bf(acc[7] * inv) << 16);
    *(uint4*)(meanb + (size_t)seg * DIM + lane * 8) = o;
}

// ===== 128x128 GEMM, 64KB LDS, 2 blocks/CU (round-10) =====
// 940 blocks x 256 threads (4 waves 2Mx2N), per-wave C = 64x64 (acc[4][4]).
// LDS 64KB/block: buf{0,1} x {A-k0,A-k1,B-k0,B-k1} x [128 rows][32 shorts] (8KB slots).
// Mechanism: 2 resident blocks/CU -> one block's waves fill MFMA/LDS pipes while the
// other drains barriers/vmcnt (m114 implicit overlap), on top of R9's gap-2 slack.
// Uniform 4-phase schedule (iter = 2 K-tiles; blocks denote textual position):
//   ph1: read b0-k0 | stage b1{A,B}k0(t1) | VMC4       (guards ph2 reads: prev L13-16)
//   ph2: read b0-k1 | stage b1{A,B}k1(t1) | VMC4       (guards ph3 reads: L1-4)
//   ph3: read b1-k0 | stage b0{A,B}k0(t2) | VMC4       (guards ph4 reads: L5-8)
//   ph4: read b1-k1 | stage b0{A,B}k1(t2) | VMC4       (guards ph1' reads: L9-12)
// WAR: every slot's restage block = its last-read block + 2 (single-barrier-safe, R9
// proof). RAW: 4 loads/phase; VMC4 after stages completes thru the load each upcoming
// read needs (hand-verified, incl. prologue VMC0; tail ph3/ph4 degrade to VMC0).
// Swizzle: both-sides involution chunk ^= (row+(row>>2))&3; stage layout is row-major
// addr(row,c)=row*32+c*8 via lane-linear GLD16 (verified: j*2048+w*512+l*8 == row*32+c*8).

#define GLD16(g, l)                                                                     \
    __builtin_amdgcn_global_load_lds((const __attribute__((address_space(1))) void*)(g), \
                                     (__attribute__((address_space(3))) void*)(l), 16, 0, 0)

// slot offsets in shorts: A-k0=0, A-k1=4096, B-k0=8192, B-k1=12288; BUF1=16384
#define STAGE_A(tile, ksh, bufo) do {                                                   \
    int _pt = (tile) >> 3;                                                              \
    const unsigned short* _ab = (_pt == 0) ? xb : meanb + (size_t)(_pt - 1) * N_NODES * DIM; \
    int _kc = (((tile) & 7) << 6) + ((ksh) << 5) + gcol;  /* part-relative col */       \
    int _g0 = m0 + srow; if (_g0 >= N_NODES) _g0 = 0;                                   \
    int _g1 = m0 + srow + 64; if (_g1 >= N_NODES) _g1 = 0;                              \
    GLD16(_ab + (size_t)_g0 * DIM + _kc, S + (bufo) + ((ksh) << 12) + (wid << 9));      \
    GLD16(_ab + (size_t)_g1 * DIM + _kc, S + (bufo) + ((ksh) << 12) + 2048 + (wid << 9)); \
} while (0)

#define STAGE_B(tile, ksh, bufo) do {                                                   \
    int _kc = ((tile) << 6) + ((ksh) << 5) + gcol;        /* FULL k into wt */          \
    const unsigned short* _w0 = wt + (size_t)(n0 + srow) * KTOT + _kc;                  \
    GLD16(_w0, S + (bufo) + 8192 + ((ksh) << 12) + (wid << 9));                         \
    GLD16(_w0 + (size_t)64 * KTOT, S + (bufo) + 8192 + ((ksh) << 12) + 2048 + (wid << 9)); \
} while (0)

// arowF/brow0 PRE-multiplied row bases (shorts); frag stride 16 rows = 512 shorts.
#define READ_A(ks, bufo) do {                                                           \
    const unsigned short* _ap = S + (bufo) + ((ks) << 12) + arowF + cofs;               \
    a[0] = *(const short8*)(_ap);                                                       \
    a[1] = *(const short8*)(_ap + 512);                                                 \
    a[2] = *(const short8*)(_ap + 1024);                                                \
    a[3] = *(const short8*)(_ap + 1536);                                                \
} while (0)

#define READ_B(ks, bufo) do {                                                           \
    const unsigned short* _bp = S + (bufo) + 8192 + ((ks) << 12) + brow0 + cofs;        \
    b[0] = *(const short8*)(_bp);                                                       \
    b[1] = *(const short8*)(_bp + 512);                                                 \
    b[2] = *(const short8*)(_bp + 1024);                                                \
    b[3] = *(const short8*)(_bp + 1536);                                                \
} while (0)

#define MFMA16() do {                                                                   \
    _Pragma("unroll") for (int _m = 0; _m < 4; ++_m)                                    \
    _Pragma("unroll") for (int _n = 0; _n < 4; ++_n)                                    \
        acc[_m][_n] =                                                                   \
            __builtin_amdgcn_mfma_f32_16x16x32_bf16(a[_m], b[_n], acc[_m][_n], 0, 0, 0); \
} while (0)

#define PH_TOP()  __builtin_amdgcn_s_barrier();                                         \
                  asm volatile("s_waitcnt lgkmcnt(0)" ::: "memory");                    \
                  __builtin_amdgcn_sched_barrier(0);                                    \
                  __builtin_amdgcn_s_setprio(1)
#define PH_BOT()  __builtin_amdgcn_s_setprio(0); __builtin_amdgcn_sched_barrier(0)
#define VMC4()    asm volatile("s_waitcnt vmcnt(4)" ::: "memory")
#define VMC0()    asm volatile("s_waitcnt vmcnt(0)" ::: "memory")
#define BUF1 16384

__global__ __launch_bounds__(256, 2) void k_gemm(const unsigned short* __restrict__ xb,
                                                 const unsigned short* __restrict__ meanb,
                                                 const unsigned short* __restrict__ wt,
                                                 const float* __restrict__ bias,
                                                 float* __restrict__ outf,
                                                 unsigned short* __restrict__ xbn,
                                                 int wf32, int wbf16) {
    extern __shared__ unsigned short S[];  // 65536 B
    int tid = threadIdx.x;
    int lane = tid & 63, wid = tid >> 6;

    // bijective XCD swizzle (m204): bn fastest -> the 4 col-blocks of a row-panel
    // land consecutively on the same XCD's L2 (A-panel fetched once per XCD).
    int orig = blockIdx.x;
    int xcd = orig & 7, tix = orig >> 3;
    const int q = NWG_GEMM >> 3, r = NWG_GEMM & 7;  // 117, 4
    int wgid = (xcd < r ? xcd * (q + 1) : r * (q + 1) + (xcd - r) * q) + tix;
    int bn = wgid & 3, bm = wgid >> 2;
    int m0 = bm * 128, n0 = bn * 128;
    int wm = wid >> 1, wn = wid & 1;

    // ds_read-side constants; swizzle f depends only on r15 (invariant under +16k rows)
    int r15 = lane & 15, c4 = lane >> 4;
    int f = (r15 + (r15 >> 2)) & 3;
    int cofs = ((c4 ^ f) << 3);              // shorts
    int arowF = (wm * 64 + r15) * 32;        // row base, shorts
    int brow0 = (wn * 64 + r15) * 32;

    // stage-side constants: srow in [0,64), second GLD16 covers +64 (f invariant +64)
    int srow = (wid << 4) + (lane >> 2);     // 0..63
    int f_t = (srow + (srow >> 2)) & 3;
    int gcol = (((lane & 3) ^ f_t) << 3);    // pre-swizzled global source col (elements)

    short8 a[4], b[4];
    f32x4 acc[4][4] = {};

    // prologue: tile0 all 4 slots -> buf0 (8 loads/wave); drain; barrier.
    STAGE_A(0, 0, 0); STAGE_B(0, 0, 0); STAGE_A(0, 1, 0); STAGE_B(0, 1, 0);
    VMC0();
    __builtin_amdgcn_s_barrier();

    for (int it = 0; it < NT / 2; ++it) {
        int t1 = 2 * it + 1, t2 = 2 * it + 2;   // t1 < NT always
        // ph1: read b0-k0 | stage b1{A,B}k0(t1) [L1-4] | VMC4
        READ_A(0, 0); READ_B(0, 0);
        STAGE_A(t1, 0, BUF1); STAGE_B(t1, 0, BUF1);
        VMC4();
        PH_TOP(); MFMA16(); PH_BOT();
        // ph2: read b0-k1 | stage b1{A,B}k1(t1) [L5-8] | VMC4
        READ_A(1, 0); READ_B(1, 0);
        STAGE_A(t1, 1, BUF1); STAGE_B(t1, 1, BUF1);
        VMC4();
        PH_TOP(); MFMA16(); PH_BOT();
        // ph3: read b1-k0 | stage b0{A,B}k0(t2) [L9-12] | VMC4 (tail: VMC0)
        READ_A(0, BUF1); READ_B(0, BUF1);
        if (t2 < NT) { STAGE_A(t2, 0, 0); STAGE_B(t2, 0, 0); VMC4(); } else { VMC0(); }
        PH_TOP(); MFMA16(); PH_BOT();
        // ph4: read b1-k1 | stage b0{A,B}k1(t2) [L13-16] | VMC4 (tail: VMC0)
        READ_A(1, BUF1); READ_B(1, BUF1);
        if (t2 < NT) { STAGE_A(t2, 1, 0); STAGE_B(t2, 1, 0); VMC4(); } else { VMC0(); }
        PH_TOP(); MFMA16(); PH_BOT();
    }
    VMC0();

    // epilogue: bias + relu + bf16 residual (xb is also A part 0 -> cache-hot)
    #pragma unroll
    for (int m = 0; m < 4; ++m) {
        #pragma unroll
        for (int j = 0; j < 4; ++j) {
            int row = m0 + wm * 64 + m * 16 + c4 * 4 + j;
            if (row >= N_NODES) continue;
            #pragma unroll
            for (int n = 0; n < 4; ++n) {
                int col = n0 + wn * 64 + n * 16 + r15;
                float v = acc[m][n][j] + bias[col];
                v = fmaxf(v, 0.0f) + bf2f(xb[(size_t)row * DIM + col]);
                if (wf32)  outf[(size_t)row * DIM + col] = v;
                if (wbf16) xbn[(size_t)row * DIM + col] = f2bf(v);
            }
        }
    }
}

extern "C" void kernel_launch(void* const* d_in, const int* in_sizes, int n_in,
                              void* d_out, int out_size, void* d_ws, size_t ws_size,
                              hipStream_t stream) {
    const int* xidx   = (const int*)d_in[0];
    const int* eidx   = (const int*)d_in[1];
    const int* etype  = (const int*)d_in[2];
    const float* emb  = (const float*)d_in[3];
    const float* Wl[3]    = {(const float*)d_in[4], (const float*)d_in[7], (const float*)d_in[10]};
    const float* rootl[3] = {(const float*)d_in[5], (const float*)d_in[8], (const float*)d_in[11]};
    const float* bl[3]    = {(const float*)d_in[6], (const float*)d_in[9], (const float*)d_in[12]};
    const int* esrc = eidx;
    const int* edst = eidx + N_EDGES;

    char* ws = (char*)d_ws;
    size_t off = 0;
    auto take = [&](size_t bytes) { char* p = ws + off; off = (off + bytes + 255) & ~(size_t)255; return p; };
    unsigned short* xb0  = (unsigned short*)take((size_t)N_NODES * DIM * 2);
    unsigned short* xb1  = (unsigned short*)take((size_t)N_NODES * DIM * 2);
    unsigned short* meanb= (unsigned short*)take((size_t)NREL * N_NODES * DIM * 2);
    unsigned short* wcat = (unsigned short*)take((size_t)3 * DIM * KTOT * 2);
    int* hist    = (int*)take((size_t)NSEG * 4);      // hist+cursor adjacent: one memset
    int* cursor  = (int*)take((size_t)NSEG * 4);
    int* offsets = (int*)take((size_t)(NSEG + 1) * 4);
    int* bsums   = (int*)take(64 * 4);
    int* ssrc    = (int*)take((size_t)N_EDGES * 4);

    hipMemsetAsync(hist, 0, (size_t)2 * NSEG * 4, stream);   // hist + cursor
    for (int l = 0; l < 3; l++) {
        k_wcat<<<(DIM * KTOT + 255) / 256, 256, 0, stream>>>(Wl[l], rootl[l],
                                                             wcat + (size_t)l * DIM * KTOT);
    }
    k_embed<<<(N_NODES + 3) / 4, 256, 0, stream>>>(xidx, emb, xb0);
    k_hist<<<(N_EDGES + 255) / 256, 256, 0, stream>>>(etype, edst, hist);
    k_scan1<<<(NSEG + 2047) / 2048, 256, 0, stream>>>(hist, offsets, bsums);
    k_scan2<<<1, 64, 0, stream>>>(bsums, (NSEG + 2047) / 2048);
    k_scan3<<<(NSEG + 2047) / 2048, 256, 0, stream>>>(bsums, offsets);
    k_scatter<<<(N_EDGES + 255) / 256, 256, 0, stream>>>(etype, esrc, edst, offsets, cursor, ssrc);

    unsigned short* xb_cur = xb0;
    unsigned short* xb_nxt = xb1;
    for (int l = 0; l < 3; l++) {
        k_agg<<<N_NODES, 256, 0, stream>>>(xb_cur, ssrc, offsets, meanb);
        int last = (l == 2);
        k_gemm<<<NWG_GEMM, 256, 65536, stream>>>(xb_cur, meanb, wcat + (size_t)l * DIM * KTOT,
                                                 bl[l], (float*)d_out, xb_nxt,
                                                 last ? 1 : 0, last ? 0 : 1);
        unsigned short* t = xb_cur; xb_cur = xb_nxt; xb_nxt = t;
    }
}

// Round 11
// 610.293 us; speedup vs baseline: 1.1226x; 1.1226x over previous
//
#include <hip/hip_runtime.h>
#include <hip/hip_bf16.h>

#define N_NODES 30000
#define N_EDGES 480000
#define DIM 512
#define NREL 4
#define NSEG (NREL * N_NODES)   // 120000
#define KTOT ((NREL + 1) * DIM) // 2560
#define NT (KTOT / 64)          // 40 K-tiles of 64
#define NBM ((N_NODES + 255) / 256)  // 118
#define NWG_GEMM (NBM * 2)           // 236

typedef __attribute__((ext_vector_type(8))) short short8;
typedef __attribute__((ext_vector_type(4))) float f32x4;

__device__ __forceinline__ float bf2f(unsigned int hi) {
    union { unsigned int u; float f; } v; v.u = hi << 16; return v.f;
}
__device__ __forceinline__ unsigned short f2bf(float f) {
    union { float f; unsigned int u; } v; v.f = f;
    unsigned int u = v.u;
    unsigned int r = (u + 0x7fffu + ((u >> 16) & 1u)) >> 16;
    return (unsigned short)r;
}

// ---- prep: WcatT build via LDS transpose (round-11) ----
// Source s in [0,5): s=0 -> root[d][e], s>=1 -> W[s-1][d][e]. Output wt[e][k], k=s*512+d.
// 64x64 tile: coalesced f32 reads (lane->e), bf16 convert into T[64][66]
// (66-short pad: column read-out stride 132B = 33 dwords == 1 mod 32 banks,
// conflict-free), coalesced bf16 writes (lane->k).
__global__ __launch_bounds__(256) void k_wcat_t(const float* __restrict__ W,
                                                const float* __restrict__ root,
                                                unsigned short* __restrict__ wt) {
    __shared__ unsigned short T[64][66];
    int b = blockIdx.x;          // 0..319
    int s = b >> 6;              // 0..4
    int tile = b & 63;
    int ti = tile >> 3;          // d-tile
    int tj = tile & 7;           // e-tile
    const float* src = (s == 0) ? root : W + (size_t)(s - 1) * DIM * DIM;
    int t = threadIdx.x;
    int el = t & 63;
    int db = (t >> 6) << 4;      // 0,16,32,48
    #pragma unroll
    for (int j = 0; j < 16; j++) {
        float v = src[(size_t)(ti * 64 + db + j) * DIM + tj * 64 + el];
        T[db + j][el] = f2bf(v);
    }
    __syncthreads();
    int dl = t & 63;
    int eb = (t >> 6) << 4;
    #pragma unroll
    for (int j = 0; j < 16; j++) {
        wt[(size_t)(tj * 64 + eb + j) * KTOT + s * 512 + ti * 64 + dl] = T[dl][eb + j];
    }
}

// ---------------- prep: x0 = emb[x_idx] (bf16 only); 4 nodes per 256-thread block ----
__global__ void k_embed(const int* __restrict__ xidx, const float* __restrict__ emb,
                        unsigned short* __restrict__ xb) {
    int n = blockIdx.x * 4 + (threadIdx.x >> 6);   // 7500 blocks
    int l = threadIdx.x & 63;
    if (n >= N_NODES) return;
    int id = xidx[n];
    const float4* er = (const float4*)(emb + (size_t)id * DIM + l * 8);
    float4 a = er[0], b = er[1];
    ushort4 pa, pb;
    pa.x = f2bf(a.x); pa.y = f2bf(a.y); pa.z = f2bf(a.z); pa.w = f2bf(a.w);
    pb.x = f2bf(b.x); pb.y = f2bf(b.y); pb.z = f2bf(b.z); pb.w = f2bf(b.w);
    ushort4* xbo = (ushort4*)(xb + (size_t)n * DIM + l * 8);
    xbo[0] = pa; xbo[1] = pb;
}

// ---------------- counting sort of edges by seg = etype*N + dst ----------------
__global__ void k_hist(const int* __restrict__ etype, const int* __restrict__ dst,
                       int* __restrict__ hist) {
    int e = blockIdx.x * 256 + threadIdx.x;
    if (e < N_EDGES) atomicAdd(&hist[etype[e] * N_NODES + dst[e]], 1);
}

__global__ void k_scan1(const int* __restrict__ hist, int* __restrict__ offsets,
                        int* __restrict__ bsums) {
    __shared__ int sdata[256];
    int t = threadIdx.x, b = blockIdx.x;
    int base = b * 2048 + t * 8;
    int v[8]; int s = 0;
    #pragma unroll
    for (int i = 0; i < 8; i++) {
        int idx = base + i;
        v[i] = (idx < NSEG) ? hist[idx] : 0;
        s += v[i];
    }
    sdata[t] = s; __syncthreads();
    for (int off = 1; off < 256; off <<= 1) {
        int x = (t >= off) ? sdata[t - off] : 0;
        __syncthreads();
        sdata[t] += x;
        __syncthreads();
    }
    int run = (t == 0) ? 0 : sdata[t - 1];
    #pragma unroll
    for (int i = 0; i < 8; i++) {
        run += v[i];
        int idx = base + i;
        if (idx < NSEG) offsets[idx + 1] = run;
    }
    if (t == 255) bsums[b] = sdata[255];
}

__global__ void k_scan2(int* __restrict__ bsums, int nb) {
    if (threadIdx.x == 0 && blockIdx.x == 0) {
        int run = 0;
        for (int i = 0; i < nb; i++) { int v = bsums[i]; bsums[i] = run; run += v; }
    }
}

__global__ void k_scan3(const int* __restrict__ bsums, int* __restrict__ offsets) {
    int t = threadIdx.x, b = blockIdx.x;
    int base = b * 2048 + t * 8;
    int add = bsums[b];
    #pragma unroll
    for (int i = 0; i < 8; i++) {
        int idx = base + i;
        if (idx < NSEG) offsets[idx + 1] += add;
    }
    if (b == 0 && t == 0) offsets[0] = 0;
}

__global__ void k_scatter(const int* __restrict__ etype, const int* __restrict__ src,
                          const int* __restrict__ dst, const int* __restrict__ offsets,
                          int* __restrict__ cursor, int* __restrict__ ssrc) {
    int e = blockIdx.x * 256 + threadIdx.x;
    if (e < N_EDGES) {
        int seg = etype[e] * N_NODES + dst[e];
        int p = atomicAdd(&cursor[seg], 1);
        ssrc[offsets[seg] + p] = src[e];
    }
}

// ---------------- per-layer segment-mean (reads bf16 x, writes bf16 mean) ----------------
__global__ __launch_bounds__(256) void k_agg(const unsigned short* __restrict__ xb,
                                             const int* __restrict__ ssrc,
                                             const int* __restrict__ offsets,
                                             unsigned short* __restrict__ meanb) {
    int wid = threadIdx.x >> 6, lane = threadIdx.x & 63;
    int seg = blockIdx.x * 4 + wid;
    int st = offsets[seg], en = offsets[seg + 1];
    float acc[8] = {0, 0, 0, 0, 0, 0, 0, 0};
    int i = st;
    for (; i + 1 < en; i += 2) {
        int s0 = ssrc[i], s1 = ssrc[i + 1];
        uint4 v0 = *(const uint4*)(xb + (size_t)s0 * DIM + lane * 8);
        uint4 v1 = *(const uint4*)(xb + (size_t)s1 * DIM + lane * 8);
        acc[0] += bf2f(v0.x & 0xffffu) + bf2f(v1.x & 0xffffu);
        acc[1] += bf2f(v0.x >> 16)     + bf2f(v1.x >> 16);
        acc[2] += bf2f(v0.y & 0xffffu) + bf2f(v1.y & 0xffffu);
        acc[3] += bf2f(v0.y >> 16)     + bf2f(v1.y >> 16);
        acc[4] += bf2f(v0.z & 0xffffu) + bf2f(v1.z & 0xffffu);
        acc[5] += bf2f(v0.z >> 16)     + bf2f(v1.z >> 16);
        acc[6] += bf2f(v0.w & 0xffffu) + bf2f(v1.w & 0xffffu);
        acc[7] += bf2f(v0.w >> 16)     + bf2f(v1.w >> 16);
    }
    if (i < en) {
        int s = ssrc[i];
        uint4 v = *(const uint4*)(xb + (size_t)s * DIM + lane * 8);
        acc[0] += bf2f(v.x & 0xffffu); acc[1] += bf2f(v.x >> 16);
        acc[2] += bf2f(v.y & 0xffffu); acc[3] += bf2f(v.y >> 16);
        acc[4] += bf2f(v.z & 0xffffu); acc[5] += bf2f(v.z >> 16);
        acc[6] += bf2f(v.w & 0xffffu); acc[7] += bf2f(v.w >> 16);
    }
    float inv = (en > st) ? 1.0f / (float)(en - st) : 0.0f;
    uint4 o;
    o.x = (unsigned int)f2bf(acc[0] * inv) | ((unsigned int)f2bf(acc[1] * inv) << 16);
    o.y = (unsigned int)f2bf(acc[2] * inv) | ((unsigned int)f2bf(acc[3] * inv) << 16);
    o.z = (unsigned int)f2bf(acc[4] * inv) | ((unsigned int)f2bf(acc[5] * inv) << 16);
    o.w = (unsigned int)f2bf(acc[6] * inv) | ((unsigned int)f2bf(acc[7] * inv) << 16);
    *(uint4*)(meanb + (size_t)seg * DIM + lane * 8) = o;
}

// ===== 8-phase 256x256 GEMM — gap-2 slot schedule, SINGLE barrier/phase (R9 champion) ====
// See R9 notes: stages shifted so every slot's restage is >=2 regions after its last
// read (WAR safe with only the TOP barrier); RAW via VMC6 at ph2/4/6/8 (hand-verified
// ledger); tail degrades to VMC0. Swizzle: both-sides involution chunk ^= (row+row>>2)&3.

#define GLD16(g, l)                                                                     \
    __builtin_amdgcn_global_load_lds((const __attribute__((address_space(1))) void*)(g), \
                                     (__attribute__((address_space(3))) void*)(l), 16, 0, 0)

#define STAGE_A(tile, ksh, bufo) do {                                                   \
    int _pt = (tile) >> 3;                                                              \
    const unsigned short* _ab = (_pt == 0) ? xb : meanb + (size_t)(_pt - 1) * N_NODES * DIM; \
    int _kc = (((tile) & 7) << 6) + ((ksh) << 5) + gcol;  /* part-relative col */       \
    int _g0 = m0 + srow; if (_g0 >= N_NODES) _g0 = 0;                                   \
    int _g1 = m0 + srow + 128; if (_g1 >= N_NODES) _g1 = 0;                             \
    GLD16(_ab + (size_t)_g0 * DIM + _kc, S + (bufo) + ((ksh) * 8192) + (wid << 9));     \
    GLD16(_ab + (size_t)_g1 * DIM + _kc, S + (bufo) + ((ksh) * 8192) + 4096 + (wid << 9)); \
} while (0)

#define STAGE_B(tile, ksh, bufo) do {                                                   \
    int _kc = ((tile) << 6) + ((ksh) << 5) + gcol;        /* FULL k into wt */          \
    const unsigned short* _w0 = wt + (size_t)(n0 + srow) * KTOT + _kc;                  \
    GLD16(_w0, S + (bufo) + 16384 + ((ksh) * 8192) + (wid << 9));                       \
    GLD16(_w0 + (size_t)128 * KTOT, S + (bufo) + 16384 + ((ksh) * 8192) + 4096 + (wid << 9)); \
} while (0)

// arowF/brow0 are PRE-multiplied row bases (shorts). mq offset = 64 rows = 2048 shorts.
#define READ_A(mq, ks, bufo) do {                                                       \
    const unsigned short* _ap = S + (bufo) + (ks) * 8192 + arowF + (mq) * 2048 + cofs;  \
    a[0] = *(const short8*)(_ap);                                                       \
    a[1] = *(const short8*)(_ap + 512);                                                 \
    a[2] = *(const short8*)(_ap + 1024);                                                \
    a[3] = *(const short8*)(_ap + 1536);                                                \
} while (0)

#define READ_B(ks, bufo) do {                                                           \
    const unsigned short* _bp = S + (bufo) + 16384 + (ks) * 8192 + brow0 + cofs;        \
    b[0] = *(const short8*)(_bp);                                                       \
    b[1] = *(const short8*)(_bp + 512);                                                 \
    b[2] = *(const short8*)(_bp + 1024);                                                \
    b[3] = *(const short8*)(_bp + 1536);                                                \
} while (0)

#define MFMA16(mq) do {                                                                 \
    _Pragma("unroll") for (int _m = 0; _m < 4; ++_m)                                    \
    _Pragma("unroll") for (int _n = 0; _n < 4; ++_n)                                    \
        acc[(mq) * 4 + _m][_n] =                                                        \
            __builtin_amdgcn_mfma_f32_16x16x32_bf16(a[_m], b[_n], acc[(mq) * 4 + _m][_n], 0, 0, 0); \
} while (0)

// single barrier per phase; sched_barrier pins program order at both edges
#define PH_TOP()  __builtin_amdgcn_s_barrier();                                         \
                  asm volatile("s_waitcnt lgkmcnt(0)" ::: "memory");                    \
                  __builtin_amdgcn_sched_barrier(0);                                    \
                  __builtin_amdgcn_s_setprio(1)
#define PH_BOT()  __builtin_amdgcn_s_setprio(0); __builtin_amdgcn_sched_barrier(0)
#define VMC6()    asm volatile("s_waitcnt vmcnt(6)" ::: "memory")
#define VMC4()    asm volatile("s_waitcnt vmcnt(4)" ::: "memory")
#define VMC0()    asm volatile("s_waitcnt vmcnt(0)" ::: "memory")
#define BUF1 32768

__global__ __launch_bounds__(512, 2) void k_gemm(const unsigned short* __restrict__ xb,
                                                 const unsigned short* __restrict__ meanb,
                                                 const unsigned short* __restrict__ wt,
                                                 const float* __restrict__ bias,
                                                 float* __restrict__ outf,
                                                 unsigned short* __restrict__ xbn,
                                                 int wf32, int wbf16) {
    extern __shared__ unsigned short S[];  // 131072 B
    int tid = threadIdx.x;
    int lane = tid & 63, wid = tid >> 6;

    // bijective XCD swizzle (m204)
    int orig = blockIdx.x;
    int xcd = orig & 7, tix = orig >> 3;
    const int q = NWG_GEMM >> 3, r = NWG_GEMM & 7;  // 29, 4
    int wgid = (xcd < r ? xcd * (q + 1) : r * (q + 1) + (xcd - r) * q) + tix;
    int bn = wgid & 1, bm = wgid >> 1;
    int m0 = bm * 256, n0 = bn * 256;
    int wm = wid >> 2, wn = wid & 3;

    // ds_read-side constants; swizzle f depends only on r15 (invariant under +16k rows)
    int r15 = lane & 15, c4 = lane >> 4;
    int f = (r15 + (r15 >> 2)) & 3;
    int cofs = ((c4 ^ f) << 3);              // shorts
    int arowF = (wm * 128 + r15) * 32;       // row base, shorts
    int brow0 = (wn * 64 + r15) * 32;

    // stage-side constants (f_t invariant under +128 rows)
    int srow = tid >> 2;                     // 0..127
    int f_t = (srow + (srow >> 2)) & 3;
    int gcol = (((tid & 3) ^ f_t) << 3);     // pre-swizzled global source col (elements)

    short8 a[4], b[4];
    f32x4 acc[8][4] = {};

    // prologue: tile0 all 4 slots -> buf0 (loads 1-8); tile1 k0 slots -> buf1 (9-12).
    // VMC4 -> thru load 8: tile0 fully landed.
    STAGE_B(0, 0, 0); STAGE_A(0, 0, 0); STAGE_B(0, 1, 0); STAGE_A(0, 1, 0);
    STAGE_B(1, 0, BUF1); STAGE_A(1, 0, BUF1);
    VMC4();
    __builtin_amdgcn_s_barrier();

    for (int it = 0; it < NT / 2; ++it) {
        int t1 = 2 * it + 1, t2 = 2 * it + 2, t3 = 2 * it + 3;  // t1 < NT always
        // ph1: read b0-k0 mq0 + B | stage B(t1,k1,b1)
        READ_A(0, 0, 0); READ_B(0, 0);
        STAGE_B(t1, 1, BUF1);
        PH_TOP(); MFMA16(0); PH_BOT();
        // ph2: read b0-k0 mq1 | VMC6 (-> thru ph6 of prev iter)
        READ_A(1, 0, 0);
        VMC6();
        PH_TOP(); MFMA16(1); PH_BOT();
        // ph3: read b0-k1 mq0 + B | stage A(t1,k1,b1) then B(t2,k0,b0)
        READ_A(0, 1, 0); READ_B(1, 0);
        STAGE_A(t1, 1, BUF1);
        if (t2 < NT) STAGE_B(t2, 0, 0);
        PH_TOP(); MFMA16(0); PH_BOT();
        // ph4: read b0-k1 mq1 | stage A(t2,k0,b0) | VMC6 (-> thru ph1 this iter)
        READ_A(1, 1, 0);
        if (t2 < NT) { STAGE_A(t2, 0, 0); VMC6(); } else { VMC0(); }
        PH_TOP(); MFMA16(1); PH_BOT();
        // ph5: read b1-k0 mq0 + B | stage B(t2,k1,b0)
        READ_A(0, 0, BUF1); READ_B(0, BUF1);
        if (t2 < NT) STAGE_B(t2, 1, 0);
        PH_TOP(); MFMA16(0); PH_BOT();
        // ph6: read b1-k0 mq1 | stage A(t2,k1,b0) | VMC6 (-> thru ph3 this iter)
        READ_A(1, 0, BUF1);
        if (t2 < NT) { STAGE_A(t2, 1, 0); VMC6(); } else { VMC0(); }
        PH_TOP(); MFMA16(1); PH_BOT();
        // ph7: read b1-k1 mq0 + B | stage B(t3,k0,b1)
        READ_A(0, 1, BUF1); READ_B(1, BUF1);
        if (t3 < NT) STAGE_B(t3, 0, BUF1);
        PH_TOP(); MFMA16(0); PH_BOT();
        // ph8: read b1-k1 mq1 | stage A(t3,k0,b1) | VMC6 (-> thru ph5 this iter)
        READ_A(1, 1, BUF1);
        if (t3 < NT) { STAGE_A(t3, 0, BUF1); VMC6(); } else { VMC0(); }
        PH_TOP(); MFMA16(1); PH_BOT();
    }
    VMC0();

    // epilogue: bias + relu + bf16 residual (xb is also A part 0 -> cache-hot)
    #pragma unroll
    for (int mm = 0; mm < 8; ++mm) {
        int rowoff = ((mm >> 2) << 6) + ((mm & 3) << 4);
        #pragma unroll
        for (int j = 0; j < 4; ++j) {
            int row = m0 + wm * 128 + rowoff + c4 * 4 + j;
            if (row >= N_NODES) continue;
            #pragma unroll
            for (int n = 0; n < 4; ++n) {
                int col = n0 + wn * 64 + n * 16 + r15;
                float v = acc[mm][n][j] + bias[col];
                v = fmaxf(v, 0.0f) + bf2f(xb[(size_t)row * DIM + col]);
                if (wf32)  outf[(size_t)row * DIM + col] = v;
                if (wbf16) xbn[(size_t)row * DIM + col] = f2bf(v);
            }
        }
    }
}

extern "C" void kernel_launch(void* const* d_in, const int* in_sizes, int n_in,
                              void* d_out, int out_size, void* d_ws, size_t ws_size,
                              hipStream_t stream) {
    const int* xidx   = (const int*)d_in[0];
    const int* eidx   = (const int*)d_in[1];
    const int* etype  = (const int*)d_in[2];
    const float* emb  = (const float*)d_in[3];
    const float* Wl[3]    = {(const float*)d_in[4], (const float*)d_in[7], (const float*)d_in[10]};
    const float* rootl[3] = {(const float*)d_in[5], (const float*)d_in[8], (const float*)d_in[11]};
    const float* bl[3]    = {(const float*)d_in[6], (const float*)d_in[9], (const float*)d_in[12]};
    const int* esrc = eidx;
    const int* edst = eidx + N_EDGES;

    char* ws = (char*)d_ws;
    size_t off = 0;
    auto take = [&](size_t bytes) { char* p = ws + off; off = (off + bytes + 255) & ~(size_t)255; return p; };
    unsigned short* xb0  = (unsigned short*)take((size_t)N_NODES * DIM * 2);
    unsigned short* xb1  = (unsigned short*)take((size_t)N_NODES * DIM * 2);
    unsigned short* meanb= (unsigned short*)take((size_t)NREL * N_NODES * DIM * 2);
    unsigned short* wcat = (unsigned short*)take((size_t)3 * DIM * KTOT * 2);
    int* hist    = (int*)take((size_t)NSEG * 4);      // hist+cursor adjacent: one memset
    int* cursor  = (int*)take((size_t)NSEG * 4);
    int* offsets = (int*)take((size_t)(NSEG + 1) * 4);
    int* bsums   = (int*)take(64 * 4);
    int* ssrc    = (int*)take((size_t)N_EDGES * 4);

    hipMemsetAsync(hist, 0, (size_t)2 * NSEG * 4, stream);   // hist + cursor
    for (int l = 0; l < 3; l++) {
        k_wcat_t<<<320, 256, 0, stream>>>(Wl[l], rootl[l], wcat + (size_t)l * DIM * KTOT);
    }
    k_embed<<<(N_NODES + 3) / 4, 256, 0, stream>>>(xidx, emb, xb0);
    k_hist<<<(N_EDGES + 255) / 256, 256, 0, stream>>>(etype, edst, hist);
    k_scan1<<<(NSEG + 2047) / 2048, 256, 0, stream>>>(hist, offsets, bsums);
    k_scan2<<<1, 64, 0, stream>>>(bsums, (NSEG + 2047) / 2048);
    k_scan3<<<(NSEG + 2047) / 2048, 256, 0, stream>>>(bsums, offsets);
    k_scatter<<<(N_EDGES + 255) / 256, 256, 0, stream>>>(etype, esrc, edst, offsets, cursor, ssrc);

    unsigned short* xb_cur = xb0;
    unsigned short* xb_nxt = xb1;
    for (int l = 0; l < 3; l++) {
        k_agg<<<N_NODES, 256, 0, stream>>>(xb_cur, ssrc, offsets, meanb);
        int last = (l == 2);
        k_gemm<<<NWG_GEMM, 512, 131072, stream>>>(xb_cur, meanb, wcat + (size_t)l * DIM * KTOT,
                                                  bl[l], (float*)d_out, xb_nxt,
                                                  last ? 1 : 0, last ? 0 : 1);
        unsigned short* t = xb_cur; xb_cur = xb_nxt; xb_nxt = t;
    }
}

// Round 12
// 602.136 us; speedup vs baseline: 1.1378x; 1.0135x over previous
//
#include <hip/hip_runtime.h>
#include <hip/hip_bf16.h>

#define N_NODES 30000
#define N_EDGES 480000
#define DIM 512
#define NREL 4
#define NSEG (NREL * N_NODES)   // 120000
#define KTOT ((NREL + 1) * DIM) // 2560
#define NT (KTOT / 64)          // 40 K-tiles of 64
#define NBM ((N_NODES + 255) / 256)  // 118
#define NWG_GEMM (NBM * 2)           // 236
#define NB_EMBED ((N_NODES + 3) / 4)       // 7500
#define NB_HIST ((N_EDGES + 255) / 256)    // 1875
#define NB_SCAN ((NSEG + 2047) / 2048)     // 59

typedef __attribute__((ext_vector_type(8))) short short8;
typedef __attribute__((ext_vector_type(4))) float f32x4;

__device__ __forceinline__ float bf2f(unsigned int hi) {
    union { unsigned int u; float f; } v; v.u = hi << 16; return v.f;
}
__device__ __forceinline__ unsigned short f2bf(float f) {
    union { float f; unsigned int u; } v; v.f = f;
    unsigned int u = v.u;
    unsigned int r = (u + 0x7fffu + ((u >> 16) & 1u)) >> 16;
    return (unsigned short)r;
}

// ---- prep: WcatT build via LDS transpose ----
// Source s in [0,5): s=0 -> root[d][e], s>=1 -> W[s-1][d][e]. Output wt[e][k], k=s*512+d.
// 64x64 tile: coalesced f32 reads (lane->e), bf16 convert into T[64][66] (pad 66:
// column stride 33 dwords == 1 mod 32 banks, conflict-free), coalesced bf16 writes.
__global__ __launch_bounds__(256) void k_wcat_t(const float* __restrict__ W,
                                                const float* __restrict__ root,
                                                unsigned short* __restrict__ wt) {
    __shared__ unsigned short T[64][66];
    int b = blockIdx.x;          // 0..319
    int s = b >> 6;              // 0..4
    int tile = b & 63;
    int ti = tile >> 3;          // d-tile
    int tj = tile & 7;           // e-tile
    const float* src = (s == 0) ? root : W + (size_t)(s - 1) * DIM * DIM;
    int t = threadIdx.x;
    int el = t & 63;
    int db = (t >> 6) << 4;      // 0,16,32,48
    #pragma unroll
    for (int j = 0; j < 16; j++) {
        float v = src[(size_t)(ti * 64 + db + j) * DIM + tj * 64 + el];
        T[db + j][el] = f2bf(v);
    }
    __syncthreads();
    int dl = t & 63;
    int eb = (t >> 6) << 4;
    #pragma unroll
    for (int j = 0; j < 16; j++) {
        wt[(size_t)(tj * 64 + eb + j) * KTOT + s * 512 + ti * 64 + dl] = T[dl][eb + j];
    }
}

// ---- prep fused: blocks [0,7500): embed 4 nodes each; [7500,9375): edge histogram ----
__global__ __launch_bounds__(256) void k_prep0(const int* __restrict__ xidx,
                                               const float* __restrict__ emb,
                                               unsigned short* __restrict__ xb,
                                               const int* __restrict__ etype,
                                               const int* __restrict__ dst,
                                               int* __restrict__ hist) {
    int b = blockIdx.x;
    if (b < NB_EMBED) {
        int n = b * 4 + (threadIdx.x >> 6);
        int l = threadIdx.x & 63;
        if (n >= N_NODES) return;
        int id = xidx[n];
        const float4* er = (const float4*)(emb + (size_t)id * DIM + l * 8);
        float4 a = er[0], bb = er[1];
        ushort4 pa, pb;
        pa.x = f2bf(a.x); pa.y = f2bf(a.y); pa.z = f2bf(a.z); pa.w = f2bf(a.w);
        pb.x = f2bf(bb.x); pb.y = f2bf(bb.y); pb.z = f2bf(bb.z); pb.w = f2bf(bb.w);
        ushort4* xbo = (ushort4*)(xb + (size_t)n * DIM + l * 8);
        xbo[0] = pa; xbo[1] = pb;
    } else {
        int e = (b - NB_EMBED) * 256 + threadIdx.x;
        if (e < N_EDGES) atomicAdd(&hist[etype[e] * N_NODES + dst[e]], 1);
    }
}

// ---------------- counting sort: block-local scan ----------------
__global__ void k_scan1(const int* __restrict__ hist, int* __restrict__ offsets,
                        int* __restrict__ bsums) {
    __shared__ int sdata[256];
    int t = threadIdx.x, b = blockIdx.x;
    int base = b * 2048 + t * 8;
    int v[8]; int s = 0;
    #pragma unroll
    for (int i = 0; i < 8; i++) {
        int idx = base + i;
        v[i] = (idx < NSEG) ? hist[idx] : 0;
        s += v[i];
    }
    sdata[t] = s; __syncthreads();
    for (int off = 1; off < 256; off <<= 1) {
        int x = (t >= off) ? sdata[t - off] : 0;
        __syncthreads();
        sdata[t] += x;
        __syncthreads();
    }
    int run = (t == 0) ? 0 : sdata[t - 1];
    #pragma unroll
    for (int i = 0; i < 8; i++) {
        run += v[i];
        int idx = base + i;
        if (idx < NSEG) offsets[idx + 1] = run;
    }
    if (t == 255) bsums[b] = sdata[255];
}

// scan3 with inlined block-prefix (scan2 eliminated): each block scalar-sums
// bsums[0..b) (<=58 uniform loads) then adds to its offset range.
__global__ void k_scan3(const int* __restrict__ bsums, int* __restrict__ offsets) {
    int t = threadIdx.x, b = blockIdx.x;
    int add = 0;
    for (int i = 0; i < b; i++) add += bsums[i];
    int base = b * 2048 + t * 8;
    #pragma unroll
    for (int i = 0; i < 8; i++) {
        int idx = base + i;
        if (idx < NSEG) offsets[idx + 1] += add;
    }
    if (b == 0 && t == 0) offsets[0] = 0;
}

__global__ void k_scatter(const int* __restrict__ etype, const int* __restrict__ src,
                          const int* __restrict__ dst, const int* __restrict__ offsets,
                          int* __restrict__ cursor, int* __restrict__ ssrc) {
    int e = blockIdx.x * 256 + threadIdx.x;
    if (e < N_EDGES) {
        int seg = etype[e] * N_NODES + dst[e];
        int p = atomicAdd(&cursor[seg], 1);
        ssrc[offsets[seg] + p] = src[e];
    }
}

// ---------------- per-layer segment-mean (4-deep ILP gather) ----------------
__global__ __launch_bounds__(256) void k_agg(const unsigned short* __restrict__ xb,
                                             const int* __restrict__ ssrc,
                                             const int* __restrict__ offsets,
                                             unsigned short* __restrict__ meanb) {
    int wid = threadIdx.x >> 6, lane = threadIdx.x & 63;
    int seg = blockIdx.x * 4 + wid;
    int st = offsets[seg], en = offsets[seg + 1];
    float acc[8] = {0, 0, 0, 0, 0, 0, 0, 0};
    int i = st;
    for (; i + 3 < en; i += 4) {
        int s0 = ssrc[i], s1 = ssrc[i + 1], s2 = ssrc[i + 2], s3 = ssrc[i + 3];
        uint4 v0 = *(const uint4*)(xb + (size_t)s0 * DIM + lane * 8);
        uint4 v1 = *(const uint4*)(xb + (size_t)s1 * DIM + lane * 8);
        uint4 v2 = *(const uint4*)(xb + (size_t)s2 * DIM + lane * 8);
        uint4 v3 = *(const uint4*)(xb + (size_t)s3 * DIM + lane * 8);
        acc[0] += (bf2f(v0.x & 0xffffu) + bf2f(v1.x & 0xffffu)) + (bf2f(v2.x & 0xffffu) + bf2f(v3.x & 0xffffu));
        acc[1] += (bf2f(v0.x >> 16)     + bf2f(v1.x >> 16))     + (bf2f(v2.x >> 16)     + bf2f(v3.x >> 16));
        acc[2] += (bf2f(v0.y & 0xffffu) + bf2f(v1.y & 0xffffu)) + (bf2f(v2.y & 0xffffu) + bf2f(v3.y & 0xffffu));
        acc[3] += (bf2f(v0.y >> 16)     + bf2f(v1.y >> 16))     + (bf2f(v2.y >> 16)     + bf2f(v3.y >> 16));
        acc[4] += (bf2f(v0.z & 0xffffu) + bf2f(v1.z & 0xffffu)) + (bf2f(v2.z & 0xffffu) + bf2f(v3.z & 0xffffu));
        acc[5] += (bf2f(v0.z >> 16)     + bf2f(v1.z >> 16))     + (bf2f(v2.z >> 16)     + bf2f(v3.z >> 16));
        acc[6] += (bf2f(v0.w & 0xffffu) + bf2f(v1.w & 0xffffu)) + (bf2f(v2.w & 0xffffu) + bf2f(v3.w & 0xffffu));
        acc[7] += (bf2f(v0.w >> 16)     + bf2f(v1.w >> 16))     + (bf2f(v2.w >> 16)     + bf2f(v3.w >> 16));
    }
    for (; i + 1 < en; i += 2) {
        int s0 = ssrc[i], s1 = ssrc[i + 1];
        uint4 v0 = *(const uint4*)(xb + (size_t)s0 * DIM + lane * 8);
        uint4 v1 = *(const uint4*)(xb + (size_t)s1 * DIM + lane * 8);
        acc[0] += bf2f(v0.x & 0xffffu) + bf2f(v1.x & 0xffffu);
        acc[1] += bf2f(v0.x >> 16)     + bf2f(v1.x >> 16);
        acc[2] += bf2f(v0.y & 0xffffu) + bf2f(v1.y & 0xffffu);
        acc[3] += bf2f(v0.y >> 16)     + bf2f(v1.y >> 16);
        acc[4] += bf2f(v0.z & 0xffffu) + bf2f(v1.z & 0xffffu);
        acc[5] += bf2f(v0.z >> 16)     + bf2f(v1.z >> 16);
        acc[6] += bf2f(v0.w & 0xffffu) + bf2f(v1.w & 0xffffu);
        acc[7] += bf2f(v0.w >> 16)     + bf2f(v1.w >> 16);
    }
    if (i < en) {
        int s = ssrc[i];
        uint4 v = *(const uint4*)(xb + (size_t)s * DIM + lane * 8);
        acc[0] += bf2f(v.x & 0xffffu); acc[1] += bf2f(v.x >> 16);
        acc[2] += bf2f(v.y & 0xffffu); acc[3] += bf2f(v.y >> 16);
        acc[4] += bf2f(v.z & 0xffffu); acc[5] += bf2f(v.z >> 16);
        acc[6] += bf2f(v.w & 0xffffu); acc[7] += bf2f(v.w >> 16);
    }
    float inv = (en > st) ? 1.0f / (float)(en - st) : 0.0f;
    uint4 o;
    o.x = (unsigned int)f2bf(acc[0] * inv) | ((unsigned int)f2bf(acc[1] * inv) << 16);
    o.y = (unsigned int)f2bf(acc[2] * inv) | ((unsigned int)f2bf(acc[3] * inv) << 16);
    o.z = (unsigned int)f2bf(acc[4] * inv) | ((unsigned int)f2bf(acc[5] * inv) << 16);
    o.w = (unsigned int)f2bf(acc[6] * inv) | ((unsigned int)f2bf(acc[7] * inv) << 16);
    *(uint4*)(meanb + (size_t)seg * DIM + lane * 8) = o;
}

// ===== 8-phase 256x256 GEMM — gap-2 slot schedule, SINGLE barrier/phase (R9 champion) ====
// Stages shifted so every slot's restage is >=2 regions after its last read (WAR safe
// with only the TOP barrier); RAW via VMC6 at ph2/4/6/8 (hand-verified ledger); tail
// degrades to VMC0. Swizzle: both-sides involution chunk ^= (row+row>>2)&3.

#define GLD16(g, l)                                                                     \
    __builtin_amdgcn_global_load_lds((const __attribute__((address_space(1))) void*)(g), \
                                     (__attribute__((address_space(3))) void*)(l), 16, 0, 0)

#define STAGE_A(tile, ksh, bufo) do {                                                   \
    int _pt = (tile) >> 3;                                                              \
    const unsigned short* _ab = (_pt == 0) ? xb : meanb + (size_t)(_pt - 1) * N_NODES * DIM; \
    int _kc = (((tile) & 7) << 6) + ((ksh) << 5) + gcol;  /* part-relative col */       \
    int _g0 = m0 + srow; if (_g0 >= N_NODES) _g0 = 0;                                   \
    int _g1 = m0 + srow + 128; if (_g1 >= N_NODES) _g1 = 0;                             \
    GLD16(_ab + (size_t)_g0 * DIM + _kc, S + (bufo) + ((ksh) * 8192) + (wid << 9));     \
    GLD16(_ab + (size_t)_g1 * DIM + _kc, S + (bufo) + ((ksh) * 8192) + 4096 + (wid << 9)); \
} while (0)

#define STAGE_B(tile, ksh, bufo) do {                                                   \
    int _kc = ((tile) << 6) + ((ksh) << 5) + gcol;        /* FULL k into wt */          \
    const unsigned short* _w0 = wt + (size_t)(n0 + srow) * KTOT + _kc;                  \
    GLD16(_w0, S + (bufo) + 16384 + ((ksh) * 8192) + (wid << 9));                       \
    GLD16(_w0 + (size_t)128 * KTOT, S + (bufo) + 16384 + ((ksh) * 8192) + 4096 + (wid << 9)); \
} while (0)

#define READ_A(mq, ks, bufo) do {                                                       \
    const unsigned short* _ap = S + (bufo) + (ks) * 8192 + arowF + (mq) * 2048 + cofs;  \
    a[0] = *(const short8*)(_ap);                                                       \
    a[1] = *(const short8*)(_ap + 512);                                                 \
    a[2] = *(const short8*)(_ap + 1024);                                                \
    a[3] = *(const short8*)(_ap + 1536);                                                \
} while (0)

#define READ_B(ks, bufo) do {                                                           \
    const unsigned short* _bp = S + (bufo) + 16384 + (ks) * 8192 + brow0 + cofs;        \
    b[0] = *(const short8*)(_bp);                                                       \
    b[1] = *(const short8*)(_bp + 512);                                                 \
    b[2] = *(const short8*)(_bp + 1024);                                                \
    b[3] = *(const short8*)(_bp + 1536);                                                \
} while (0)

#define MFMA16(mq) do {                                                                 \
    _Pragma("unroll") for (int _m = 0; _m < 4; ++_m)                                    \
    _Pragma("unroll") for (int _n = 0; _n < 4; ++_n)                                    \
        acc[(mq) * 4 + _m][_n] =                                                        \
            __builtin_amdgcn_mfma_f32_16x16x32_bf16(a[_m], b[_n], acc[(mq) * 4 + _m][_n], 0, 0, 0); \
} while (0)

#define PH_TOP()  __builtin_amdgcn_s_barrier();                                         \
                  asm volatile("s_waitcnt lgkmcnt(0)" ::: "memory");                    \
                  __builtin_amdgcn_sched_barrier(0);                                    \
                  __builtin_amdgcn_s_setprio(1)
#define PH_BOT()  __builtin_amdgcn_s_setprio(0); __builtin_amdgcn_sched_barrier(0)
#define VMC6()    asm volatile("s_waitcnt vmcnt(6)" ::: "memory")
#define VMC4()    asm volatile("s_waitcnt vmcnt(4)" ::: "memory")
#define VMC0()    asm volatile("s_waitcnt vmcnt(0)" ::: "memory")
#define BUF1 32768

__global__ __launch_bounds__(512, 2) void k_gemm(const unsigned short* __restrict__ xb,
                                                 const unsigned short* __restrict__ meanb,
                                                 const unsigned short* __restrict__ wt,
                                                 const float* __restrict__ bias,
                                                 float* __restrict__ outf,
                                                 unsigned short* __restrict__ xbn,
                                                 int wf32, int wbf16) {
    extern __shared__ unsigned short S[];  // 131072 B
    int tid = threadIdx.x;
    int lane = tid & 63, wid = tid >> 6;

    // bijective XCD swizzle (m204)
    int orig = blockIdx.x;
    int xcd = orig & 7, tix = orig >> 3;
    const int q = NWG_GEMM >> 3, r = NWG_GEMM & 7;  // 29, 4
    int wgid = (xcd < r ? xcd * (q + 1) : r * (q + 1) + (xcd - r) * q) + tix;
    int bn = wgid & 1, bm = wgid >> 1;
    int m0 = bm * 256, n0 = bn * 256;
    int wm = wid >> 2, wn = wid & 3;

    int r15 = lane & 15, c4 = lane >> 4;
    int f = (r15 + (r15 >> 2)) & 3;
    int cofs = ((c4 ^ f) << 3);              // shorts
    int arowF = (wm * 128 + r15) * 32;       // row base, shorts
    int brow0 = (wn * 64 + r15) * 32;

    int srow = tid >> 2;                     // 0..127
    int f_t = (srow + (srow >> 2)) & 3;
    int gcol = (((tid & 3) ^ f_t) << 3);     // pre-swizzled global source col (elements)

    short8 a[4], b[4];
    f32x4 acc[8][4] = {};

    STAGE_B(0, 0, 0); STAGE_A(0, 0, 0); STAGE_B(0, 1, 0); STAGE_A(0, 1, 0);
    STAGE_B(1, 0, BUF1); STAGE_A(1, 0, BUF1);
    VMC4();
    __builtin_amdgcn_s_barrier();

    for (int it = 0; it < NT / 2; ++it) {
        int t1 = 2 * it + 1, t2 = 2 * it + 2, t3 = 2 * it + 3;  // t1 < NT always
        READ_A(0, 0, 0); READ_B(0, 0);
        STAGE_B(t1, 1, BUF1);
        PH_TOP(); MFMA16(0); PH_BOT();
        READ_A(1, 0, 0);
        VMC6();
        PH_TOP(); MFMA16(1); PH_BOT();
        READ_A(0, 1, 0); READ_B(1, 0);
        STAGE_A(t1, 1, BUF1);
        if (t2 < NT) STAGE_B(t2, 0, 0);
        PH_TOP(); MFMA16(0); PH_BOT();
        READ_A(1, 1, 0);
        if (t2 < NT) { STAGE_A(t2, 0, 0); VMC6(); } else { VMC0(); }
        PH_TOP(); MFMA16(1); PH_BOT();
        READ_A(0, 0, BUF1); READ_B(0, BUF1);
        if (t2 < NT) STAGE_B(t2, 1, 0);
        PH_TOP(); MFMA16(0); PH_BOT();
        READ_A(1, 0, BUF1);
        if (t2 < NT) { STAGE_A(t2, 1, 0); VMC6(); } else { VMC0(); }
        PH_TOP(); MFMA16(1); PH_BOT();
        READ_A(0, 1, BUF1); READ_B(1, BUF1);
        if (t3 < NT) STAGE_B(t3, 0, BUF1);
        PH_TOP(); MFMA16(0); PH_BOT();
        READ_A(1, 1, BUF1);
        if (t3 < NT) { STAGE_A(t3, 0, BUF1); VMC6(); } else { VMC0(); }
        PH_TOP(); MFMA16(1); PH_BOT();
    }
    VMC0();

    // epilogue: bias + relu + bf16 residual (xb is also A part 0 -> cache-hot)
    #pragma unroll
    for (int mm = 0; mm < 8; ++mm) {
        int rowoff = ((mm >> 2) << 6) + ((mm & 3) << 4);
        #pragma unroll
        for (int j = 0; j < 4; ++j) {
            int row = m0 + wm * 128 + rowoff + c4 * 4 + j;
            if (row >= N_NODES) continue;
            #pragma unroll
            for (int n = 0; n < 4; ++n) {
                int col = n0 + wn * 64 + n * 16 + r15;
                float v = acc[mm][n][j] + bias[col];
                v = fmaxf(v, 0.0f) + bf2f(xb[(size_t)row * DIM + col]);
                if (wf32)  outf[(size_t)row * DIM + col] = v;
                if (wbf16) xbn[(size_t)row * DIM + col] = f2bf(v);
            }
        }
    }
}

extern "C" void kernel_launch(void* const* d_in, const int* in_sizes, int n_in,
                              void* d_out, int out_size, void* d_ws, size_t ws_size,
                              hipStream_t stream) {
    const int* xidx   = (const int*)d_in[0];
    const int* eidx   = (const int*)d_in[1];
    const int* etype  = (const int*)d_in[2];
    const float* emb  = (const float*)d_in[3];
    const float* Wl[3]    = {(const float*)d_in[4], (const float*)d_in[7], (const float*)d_in[10]};
    const float* rootl[3] = {(const float*)d_in[5], (const float*)d_in[8], (const float*)d_in[11]};
    const float* bl[3]    = {(const float*)d_in[6], (const float*)d_in[9], (const float*)d_in[12]};
    const int* esrc = eidx;
    const int* edst = eidx + N_EDGES;

    char* ws = (char*)d_ws;
    size_t off = 0;
    auto take = [&](size_t bytes) { char* p = ws + off; off = (off + bytes + 255) & ~(size_t)255; return p; };
    unsigned short* xb0  = (unsigned short*)take((size_t)N_NODES * DIM * 2);
    unsigned short* xb1  = (unsigned short*)take((size_t)N_NODES * DIM * 2);
    unsigned short* meanb= (unsigned short*)take((size_t)NREL * N_NODES * DIM * 2);
    unsigned short* wcat = (unsigned short*)take((size_t)3 * DIM * KTOT * 2);
    int* hist    = (int*)take((size_t)NSEG * 4);      // hist+cursor adjacent: one memset
    int* cursor  = (int*)take((size_t)NSEG * 4);
    int* offsets = (int*)take((size_t)(NSEG + 1) * 4);
    int* bsums   = (int*)take(64 * 4);
    int* ssrc    = (int*)take((size_t)N_EDGES * 4);

    hipMemsetAsync(hist, 0, (size_t)2 * NSEG * 4, stream);   // hist + cursor
    for (int l = 0; l < 3; l++) {
        k_wcat_t<<<320, 256, 0, stream>>>(Wl[l], rootl[l], wcat + (size_t)l * DIM * KTOT);
    }
    k_prep0<<<NB_EMBED + NB_HIST, 256, 0, stream>>>(xidx, emb, xb0, etype, edst, hist);
    k_scan1<<<NB_SCAN, 256, 0, stream>>>(hist, offsets, bsums);
    k_scan3<<<NB_SCAN, 256, 0, stream>>>(bsums, offsets);
    k_scatter<<<NB_HIST, 256, 0, stream>>>(etype, esrc, edst, offsets, cursor, ssrc);

    unsigned short* xb_cur = xb0;
    unsigned short* xb_nxt = xb1;
    for (int l = 0; l < 3; l++) {
        k_agg<<<N_NODES, 256, 0, stream>>>(xb_cur, ssrc, offsets, meanb);
        int last = (l == 2);
        k_gemm<<<NWG_GEMM, 512, 131072, stream>>>(xb_cur, meanb, wcat + (size_t)l * DIM * KTOT,
                                                  bl[l], (float*)d_out, xb_nxt,
                                                  last ? 1 : 0, last ? 0 : 1);
        unsigned short* t = xb_cur; xb_cur = xb_nxt; xb_nxt = t;
    }
}

// Round 13
// 601.426 us; speedup vs baseline: 1.1391x; 1.0012x over previous
//
#include <hip/hip_runtime.h>
#include <hip/hip_bf16.h>

#define N_NODES 30000
#define N_EDGES 480000
#define DIM 512
#define NREL 4
#define NSEG (NREL * N_NODES)   // 120000
#define KTOT ((NREL + 1) * DIM) // 2560
#define NT (KTOT / 64)          // 40 K-tiles of 64
#define NBM ((N_NODES + 255) / 256)  // 118
#define NWG_GEMM (NBM * 2)           // 236
#define NB_EMBED ((N_NODES + 3) / 4)       // 7500
#define NB_HIST ((N_EDGES + 255) / 256)    // 1875
#define NB_SCAN ((NSEG + 2047) / 2048)     // 59

typedef __attribute__((ext_vector_type(8))) short short8;
typedef __attribute__((ext_vector_type(4))) float f32x4;

__device__ __forceinline__ float bf2f(unsigned int hi) {
    union { unsigned int u; float f; } v; v.u = hi << 16; return v.f;
}
__device__ __forceinline__ unsigned short f2bf(float f) {
    union { float f; unsigned int u; } v; v.f = f;
    unsigned int u = v.u;
    unsigned int r = (u + 0x7fffu + ((u >> 16) & 1u)) >> 16;
    return (unsigned short)r;
}

// ---- prep: WcatT build via LDS transpose ----
__global__ __launch_bounds__(256) void k_wcat_t(const float* __restrict__ W,
                                                const float* __restrict__ root,
                                                unsigned short* __restrict__ wt) {
    __shared__ unsigned short T[64][66];
    int b = blockIdx.x;          // 0..319
    int s = b >> 6;              // 0..4
    int tile = b & 63;
    int ti = tile >> 3;          // d-tile
    int tj = tile & 7;           // e-tile
    const float* src = (s == 0) ? root : W + (size_t)(s - 1) * DIM * DIM;
    int t = threadIdx.x;
    int el = t & 63;
    int db = (t >> 6) << 4;      // 0,16,32,48
    #pragma unroll
    for (int j = 0; j < 16; j++) {
        float v = src[(size_t)(ti * 64 + db + j) * DIM + tj * 64 + el];
        T[db + j][el] = f2bf(v);
    }
    __syncthreads();
    int dl = t & 63;
    int eb = (t >> 6) << 4;
    #pragma unroll
    for (int j = 0; j < 16; j++) {
        wt[(size_t)(tj * 64 + eb + j) * KTOT + s * 512 + ti * 64 + dl] = T[dl][eb + j];
    }
}

// ---- prep fused: blocks [0,7500): embed 4 nodes each; [7500,9375): edge histogram ----
__global__ __launch_bounds__(256) void k_prep0(const int* __restrict__ xidx,
                                               const float* __restrict__ emb,
                                               unsigned short* __restrict__ xb,
                                               const int* __restrict__ etype,
                                               const int* __restrict__ dst,
                                               int* __restrict__ hist) {
    int b = blockIdx.x;
    if (b < NB_EMBED) {
        int n = b * 4 + (threadIdx.x >> 6);
        int l = threadIdx.x & 63;
        if (n >= N_NODES) return;
        int id = xidx[n];
        const float4* er = (const float4*)(emb + (size_t)id * DIM + l * 8);
        float4 a = er[0], bb = er[1];
        ushort4 pa, pb;
        pa.x = f2bf(a.x); pa.y = f2bf(a.y); pa.z = f2bf(a.z); pa.w = f2bf(a.w);
        pb.x = f2bf(bb.x); pb.y = f2bf(bb.y); pb.z = f2bf(bb.z); pb.w = f2bf(bb.w);
        ushort4* xbo = (ushort4*)(xb + (size_t)n * DIM + l * 8);
        xbo[0] = pa; xbo[1] = pb;
    } else {
        int e = (b - NB_EMBED) * 256 + threadIdx.x;
        if (e < N_EDGES) atomicAdd(&hist[etype[e] * N_NODES + dst[e]], 1);
    }
}

// ---------------- counting sort: block-local scan ----------------
__global__ void k_scan1(const int* __restrict__ hist, int* __restrict__ offsets,
                        int* __restrict__ bsums) {
    __shared__ int sdata[256];
    int t = threadIdx.x, b = blockIdx.x;
    int base = b * 2048 + t * 8;
    int v[8]; int s = 0;
    #pragma unroll
    for (int i = 0; i < 8; i++) {
        int idx = base + i;
        v[i] = (idx < NSEG) ? hist[idx] : 0;
        s += v[i];
    }
    sdata[t] = s; __syncthreads();
    for (int off = 1; off < 256; off <<= 1) {
        int x = (t >= off) ? sdata[t - off] : 0;
        __syncthreads();
        sdata[t] += x;
        __syncthreads();
    }
    int run = (t == 0) ? 0 : sdata[t - 1];
    #pragma unroll
    for (int i = 0; i < 8; i++) {
        run += v[i];
        int idx = base + i;
        if (idx < NSEG) offsets[idx + 1] = run;
    }
    if (t == 255) bsums[b] = sdata[255];
}

// scan3 with inlined block-prefix (scan2 eliminated)
__global__ void k_scan3(const int* __restrict__ bsums, int* __restrict__ offsets) {
    int t = threadIdx.x, b = blockIdx.x;
    int add = 0;
    for (int i = 0; i < b; i++) add += bsums[i];
    int base = b * 2048 + t * 8;
    #pragma unroll
    for (int i = 0; i < 8; i++) {
        int idx = base + i;
        if (idx < NSEG) offsets[idx + 1] += add;
    }
    if (b == 0 && t == 0) offsets[0] = 0;
}

__global__ void k_scatter(const int* __restrict__ etype, const int* __restrict__ src,
                          const int* __restrict__ dst, const int* __restrict__ offsets,
                          int* __restrict__ cursor, int* __restrict__ ssrc) {
    int e = blockIdx.x * 256 + threadIdx.x;
    if (e < N_EDGES) {
        int seg = etype[e] * N_NODES + dst[e];
        int p = atomicAdd(&cursor[seg], 1);
        ssrc[offsets[seg] + p] = src[e];
    }
}

// ---------------- per-layer segment-mean (4-deep ILP gather) ----------------
__global__ __launch_bounds__(256) void k_agg(const unsigned short* __restrict__ xb,
                                             const int* __restrict__ ssrc,
                                             const int* __restrict__ offsets,
                                             unsigned short* __restrict__ meanb) {
    int wid = threadIdx.x >> 6, lane = threadIdx.x & 63;
    int seg = blockIdx.x * 4 + wid;
    int st = offsets[seg], en = offsets[seg + 1];
    float acc[8] = {0, 0, 0, 0, 0, 0, 0, 0};
    int i = st;
    for (; i + 3 < en; i += 4) {
        int s0 = ssrc[i], s1 = ssrc[i + 1], s2 = ssrc[i + 2], s3 = ssrc[i + 3];
        uint4 v0 = *(const uint4*)(xb + (size_t)s0 * DIM + lane * 8);
        uint4 v1 = *(const uint4*)(xb + (size_t)s1 * DIM + lane * 8);
        uint4 v2 = *(const uint4*)(xb + (size_t)s2 * DIM + lane * 8);
        uint4 v3 = *(const uint4*)(xb + (size_t)s3 * DIM + lane * 8);
        acc[0] += (bf2f(v0.x & 0xffffu) + bf2f(v1.x & 0xffffu)) + (bf2f(v2.x & 0xffffu) + bf2f(v3.x & 0xffffu));
        acc[1] += (bf2f(v0.x >> 16)     + bf2f(v1.x >> 16))     + (bf2f(v2.x >> 16)     + bf2f(v3.x >> 16));
        acc[2] += (bf2f(v0.y & 0xffffu) + bf2f(v1.y & 0xffffu)) + (bf2f(v2.y & 0xffffu) + bf2f(v3.y & 0xffffu));
        acc[3] += (bf2f(v0.y >> 16)     + bf2f(v1.y >> 16))     + (bf2f(v2.y >> 16)     + bf2f(v3.y >> 16));
        acc[4] += (bf2f(v0.z & 0xffffu) + bf2f(v1.z & 0xffffu)) + (bf2f(v2.z & 0xffffu) + bf2f(v3.z & 0xffffu));
        acc[5] += (bf2f(v0.z >> 16)     + bf2f(v1.z >> 16))     + (bf2f(v2.z >> 16)     + bf2f(v3.z >> 16));
        acc[6] += (bf2f(v0.w & 0xffffu) + bf2f(v1.w & 0xffffu)) + (bf2f(v2.w & 0xffffu) + bf2f(v3.w & 0xffffu));
        acc[7] += (bf2f(v0.w >> 16)     + bf2f(v1.w >> 16))     + (bf2f(v2.w >> 16)     + bf2f(v3.w >> 16));
    }
    for (; i + 1 < en; i += 2) {
        int s0 = ssrc[i], s1 = ssrc[i + 1];
        uint4 v0 = *(const uint4*)(xb + (size_t)s0 * DIM + lane * 8);
        uint4 v1 = *(const uint4*)(xb + (size_t)s1 * DIM + lane * 8);
        acc[0] += bf2f(v0.x & 0xffffu) + bf2f(v1.x & 0xffffu);
        acc[1] += bf2f(v0.x >> 16)     + bf2f(v1.x >> 16);
        acc[2] += bf2f(v0.y & 0xffffu) + bf2f(v1.y & 0xffffu);
        acc[3] += bf2f(v0.y >> 16)     + bf2f(v1.y >> 16);
        acc[4] += bf2f(v0.z & 0xffffu) + bf2f(v1.z & 0xffffu);
        acc[5] += bf2f(v0.z >> 16)     + bf2f(v1.z >> 16);
        acc[6] += bf2f(v0.w & 0xffffu) + bf2f(v1.w & 0xffffu);
        acc[7] += bf2f(v0.w >> 16)     + bf2f(v1.w >> 16);
    }
    if (i < en) {
        int s = ssrc[i];
        uint4 v = *(const uint4*)(xb + (size_t)s * DIM + lane * 8);
        acc[0] += bf2f(v.x & 0xffffu); acc[1] += bf2f(v.x >> 16);
        acc[2] += bf2f(v.y & 0xffffu); acc[3] += bf2f(v.y >> 16);
        acc[4] += bf2f(v.z & 0xffffu); acc[5] += bf2f(v.z >> 16);
        acc[6] += bf2f(v.w & 0xffffu); acc[7] += bf2f(v.w >> 16);
    }
    float inv = (en > st) ? 1.0f / (float)(en - st) : 0.0f;
    uint4 o;
    o.x = (unsigned int)f2bf(acc[0] * inv) | ((unsigned int)f2bf(acc[1] * inv) << 16);
    o.y = (unsigned int)f2bf(acc[2] * inv) | ((unsigned int)f2bf(acc[3] * inv) << 16);
    o.z = (unsigned int)f2bf(acc[4] * inv) | ((unsigned int)f2bf(acc[5] * inv) << 16);
    o.w = (unsigned int)f2bf(acc[6] * inv) | ((unsigned int)f2bf(acc[7] * inv) << 16);
    *(uint4*)(meanb + (size_t)seg * DIM + lane * 8) = o;
}

// ===== 8-phase 256x256 GEMM — gap-2, single barrier/phase; PH_BOT unpinned (R13) ====
// Identical to R9/R12 champion except PH_BOT no longer carries sched_barrier(0):
// there is no bottom s_barrier, so the pin was order-only; removing it lets the
// scheduler overlap the MFMA-cluster tail with the next region's ds_read issue +
// stage address VALU. Reads still cannot hoist above their guarding VMC6 (asm
// memory clobber); PH_TOP (barrier + lgkmcnt(0) + sched_barrier + setprio) intact.

#define GLD16(g, l)                                                                     \
    __builtin_amdgcn_global_load_lds((const __attribute__((address_space(1))) void*)(g), \
                                     (__attribute__((address_space(3))) void*)(l), 16, 0, 0)

#define STAGE_A(tile, ksh, bufo) do {                                                   \
    int _pt = (tile) >> 3;                                                              \
    const unsigned short* _ab = (_pt == 0) ? xb : meanb + (size_t)(_pt - 1) * N_NODES * DIM; \
    int _kc = (((tile) & 7) << 6) + ((ksh) << 5) + gcol;  /* part-relative col */       \
    int _g0 = m0 + srow; if (_g0 >= N_NODES) _g0 = 0;                                   \
    int _g1 = m0 + srow + 128; if (_g1 >= N_NODES) _g1 = 0;                             \
    GLD16(_ab + (size_t)_g0 * DIM + _kc, S + (bufo) + ((ksh) * 8192) + (wid << 9));     \
    GLD16(_ab + (size_t)_g1 * DIM + _kc, S + (bufo) + ((ksh) * 8192) + 4096 + (wid << 9)); \
} while (0)

#define STAGE_B(tile, ksh, bufo) do {                                                   \
    int _kc = ((tile) << 6) + ((ksh) << 5) + gcol;        /* FULL k into wt */          \
    const unsigned short* _w0 = wt + (size_t)(n0 + srow) * KTOT + _kc;                  \
    GLD16(_w0, S + (bufo) + 16384 + ((ksh) * 8192) + (wid << 9));                       \
    GLD16(_w0 + (size_t)128 * KTOT, S + (bufo) + 16384 + ((ksh) * 8192) + 4096 + (wid << 9)); \
} while (0)

#define READ_A(mq, ks, bufo) do {                                                       \
    const unsigned short* _ap = S + (bufo) + (ks) * 8192 + arowF + (mq) * 2048 + cofs;  \
    a[0] = *(const short8*)(_ap);                                                       \
    a[1] = *(const short8*)(_ap + 512);                                                 \
    a[2] = *(const short8*)(_ap + 1024);                                                \
    a[3] = *(const short8*)(_ap + 1536);                                                \
} while (0)

#define READ_B(ks, bufo) do {                                                           \
    const unsigned short* _bp = S + (bufo) + 16384 + (ks) * 8192 + brow0 + cofs;        \
    b[0] = *(const short8*)(_bp);                                                       \
    b[1] = *(const short8*)(_bp + 512);                                                 \
    b[2] = *(const short8*)(_bp + 1024);                                                \
    b[3] = *(const short8*)(_bp + 1536);                                                \
} while (0)

#define MFMA16(mq) do {                                                                 \
    _Pragma("unroll") for (int _m = 0; _m < 4; ++_m)                                    \
    _Pragma("unroll") for (int _n = 0; _n < 4; ++_n)                                    \
        acc[(mq) * 4 + _m][_n] =                                                        \
            __builtin_amdgcn_mfma_f32_16x16x32_bf16(a[_m], b[_n], acc[(mq) * 4 + _m][_n], 0, 0, 0); \
} while (0)

#define PH_TOP()  __builtin_amdgcn_s_barrier();                                         \
                  asm volatile("s_waitcnt lgkmcnt(0)" ::: "memory");                    \
                  __builtin_amdgcn_sched_barrier(0);                                    \
                  __builtin_amdgcn_s_setprio(1)
#define PH_BOT()  __builtin_amdgcn_s_setprio(0)
#define VMC6()    asm volatile("s_waitcnt vmcnt(6)" ::: "memory")
#define VMC4()    asm volatile("s_waitcnt vmcnt(4)" ::: "memory")
#define VMC0()    asm volatile("s_waitcnt vmcnt(0)" ::: "memory")
#define BUF1 32768

__global__ __launch_bounds__(512, 2) void k_gemm(const unsigned short* __restrict__ xb,
                                                 const unsigned short* __restrict__ meanb,
                                                 const unsigned short* __restrict__ wt,
                                                 const float* __restrict__ bias,
                                                 float* __restrict__ outf,
                                                 unsigned short* __restrict__ xbn,
                                                 int wf32, int wbf16) {
    extern __shared__ unsigned short S[];  // 131072 B
    int tid = threadIdx.x;
    int lane = tid & 63, wid = tid >> 6;

    // bijective XCD swizzle (m204)
    int orig = blockIdx.x;
    int xcd = orig & 7, tix = orig >> 3;
    const int q = NWG_GEMM >> 3, r = NWG_GEMM & 7;  // 29, 4
    int wgid = (xcd < r ? xcd * (q + 1) : r * (q + 1) + (xcd - r) * q) + tix;
    int bn = wgid & 1, bm = wgid >> 1;
    int m0 = bm * 256, n0 = bn * 256;
    int wm = wid >> 2, wn = wid & 3;

    int r15 = lane & 15, c4 = lane >> 4;
    int f = (r15 + (r15 >> 2)) & 3;
    int cofs = ((c4 ^ f) << 3);              // shorts
    int arowF = (wm * 128 + r15) * 32;       // row base, shorts
    int brow0 = (wn * 64 + r15) * 32;

    int srow = tid >> 2;                     // 0..127
    int f_t = (srow + (srow >> 2)) & 3;
    int gcol = (((tid & 3) ^ f_t) << 3);     // pre-swizzled global source col (elements)

    short8 a[4], b[4];
    f32x4 acc[8][4] = {};

    STAGE_B(0, 0, 0); STAGE_A(0, 0, 0); STAGE_B(0, 1, 0); STAGE_A(0, 1, 0);
    STAGE_B(1, 0, BUF1); STAGE_A(1, 0, BUF1);
    VMC4();
    __builtin_amdgcn_s_barrier();

    for (int it = 0; it < NT / 2; ++it) {
        int t1 = 2 * it + 1, t2 = 2 * it + 2, t3 = 2 * it + 3;  // t1 < NT always
        READ_A(0, 0, 0); READ_B(0, 0);
        STAGE_B(t1, 1, BUF1);
        PH_TOP(); MFMA16(0); PH_BOT();
        READ_A(1, 0, 0);
        VMC6();
        PH_TOP(); MFMA16(1); PH_BOT();
        READ_A(0, 1, 0); READ_B(1, 0);
        STAGE_A(t1, 1, BUF1);
        if (t2 < NT) STAGE_B(t2, 0, 0);
        PH_TOP(); MFMA16(0); PH_BOT();
        READ_A(1, 1, 0);
        if (t2 < NT) { STAGE_A(t2, 0, 0); VMC6(); } else { VMC0(); }
        PH_TOP(); MFMA16(1); PH_BOT();
        READ_A(0, 0, BUF1); READ_B(0, BUF1);
        if (t2 < NT) STAGE_B(t2, 1, 0);
        PH_TOP(); MFMA16(0); PH_BOT();
        READ_A(1, 0, BUF1);
        if (t2 < NT) { STAGE_A(t2, 1, 0); VMC6(); } else { VMC0(); }
        PH_TOP(); MFMA16(1); PH_BOT();
        READ_A(0, 1, BUF1); READ_B(1, BUF1);
        if (t3 < NT) STAGE_B(t3, 0, BUF1);
        PH_TOP(); MFMA16(0); PH_BOT();
        READ_A(1, 1, BUF1);
        if (t3 < NT) { STAGE_A(t3, 0, BUF1); VMC6(); } else { VMC0(); }
        PH_TOP(); MFMA16(1); PH_BOT();
    }
    VMC0();

    // epilogue: bias + relu + bf16 residual (xb is also A part 0 -> cache-hot)
    #pragma unroll
    for (int mm = 0; mm < 8; ++mm) {
        int rowoff = ((mm >> 2) << 6) + ((mm & 3) << 4);
        #pragma unroll
        for (int j = 0; j < 4; ++j) {
            int row = m0 + wm * 128 + rowoff + c4 * 4 + j;
            if (row >= N_NODES) continue;
            #pragma unroll
            for (int n = 0; n < 4; ++n) {
                int col = n0 + wn * 64 + n * 16 + r15;
                float v = acc[mm][n][j] + bias[col];
                v = fmaxf(v, 0.0f) + bf2f(xb[(size_t)row * DIM + col]);
                if (wf32)  outf[(size_t)row * DIM + col] = v;
                if (wbf16) xbn[(size_t)row * DIM + col] = f2bf(v);
            }
        }
    }
}

extern "C" void kernel_launch(void* const* d_in, const int* in_sizes, int n_in,
                              void* d_out, int out_size, void* d_ws, size_t ws_size,
                              hipStream_t stream) {
    const int* xidx   = (const int*)d_in[0];
    const int* eidx   = (const int*)d_in[1];
    const int* etype  = (const int*)d_in[2];
    const float* emb  = (const float*)d_in[3];
    const float* Wl[3]    = {(const float*)d_in[4], (const float*)d_in[7], (const float*)d_in[10]};
    const float* rootl[3] = {(const float*)d_in[5], (const float*)d_in[8], (const float*)d_in[11]};
    const float* bl[3]    = {(const float*)d_in[6], (const float*)d_in[9], (const float*)d_in[12]};
    const int* esrc = eidx;
    const int* edst = eidx + N_EDGES;

    char* ws = (char*)d_ws;
    size_t off = 0;
    auto take = [&](size_t bytes) { char* p = ws + off; off = (off + bytes + 255) & ~(size_t)255; return p; };
    unsigned short* xb0  = (unsigned short*)take((size_t)N_NODES * DIM * 2);
    unsigned short* xb1  = (unsigned short*)take((size_t)N_NODES * DIM * 2);
    unsigned short* meanb= (unsigned short*)take((size_t)NREL * N_NODES * DIM * 2);
    unsigned short* wcat = (unsigned short*)take((size_t)3 * DIM * KTOT * 2);
    int* hist    = (int*)take((size_t)NSEG * 4);      // hist+cursor adjacent: one memset
    int* cursor  = (int*)take((size_t)NSEG * 4);
    int* offsets = (int*)take((size_t)(NSEG + 1) * 4);
    int* bsums   = (int*)take(64 * 4);
    int* ssrc    = (int*)take((size_t)N_EDGES * 4);

    hipMemsetAsync(hist, 0, (size_t)2 * NSEG * 4, stream);   // hist + cursor
    for (int l = 0; l < 3; l++) {
        k_wcat_t<<<320, 256, 0, stream>>>(Wl[l], rootl[l], wcat + (size_t)l * DIM * KTOT);
    }
    k_prep0<<<NB_EMBED + NB_HIST, 256, 0, stream>>>(xidx, emb, xb0, etype, edst, hist);
    k_scan1<<<NB_SCAN, 256, 0, stream>>>(hist, offsets, bsums);
    k_scan3<<<NB_SCAN, 256, 0, stream>>>(bsums, offsets);
    k_scatter<<<NB_HIST, 256, 0, stream>>>(etype, esrc, edst, offsets, cursor, ssrc);

    unsigned short* xb_cur = xb0;
    unsigned short* xb_nxt = xb1;
    for (int l = 0; l < 3; l++) {
        k_agg<<<N_NODES, 256, 0, stream>>>(xb_cur, ssrc, offsets, meanb);
        int last = (l == 2);
        k_gemm<<<NWG_GEMM, 512, 131072, stream>>>(xb_cur, meanb, wcat + (size_t)l * DIM * KTOT,
                                                  bl[l], (float*)d_out, xb_nxt,
                                                  last ? 1 : 0, last ? 0 : 1);
        unsigned short* t = xb_cur; xb_cur = xb_nxt; xb_nxt = t;
    }
}